// Round 1
// baseline (514.646 us; speedup 1.0000x reference)
//
#include <hip/hip_runtime.h>
#include <hip/hip_bf16.h>
#include <stdint.h>

#define Sq   2048
#define Dq   256
#define Hq   8
#define NQKV 6144          // 3*H*D
#define HD   2048          // H*D
#define MTOK 8192          // B*S

typedef __attribute__((ext_vector_type(8))) short short8;
typedef __attribute__((ext_vector_type(4))) float f32x4;

__device__ __forceinline__ float bf2f(short v) {
  union { float f; unsigned u; } x; x.u = ((unsigned)(unsigned short)v) << 16; return x.f;
}
__device__ __forceinline__ short f2bf(float f) {
  union { float f; unsigned u; } x; x.f = f;
  unsigned r = x.u + 0x7fffu + ((x.u >> 16) & 1u);
  return (short)(r >> 16);
}
// global -> LDS direct (16B per lane); LDS dest is wave-uniform base + lane*16
__device__ __forceinline__ void gload16(const void* g, void* lds) {
  auto g1 = (const __attribute__((address_space(1))) int*)(uintptr_t)g;
  auto l3 = (__attribute__((address_space(3))) int*)(uintptr_t)lds;
  __builtin_amdgcn_global_load_lds(g1, l3, 16, 0, 0);
}

// ---------------- prep: bf16 converts + rope tables ----------------
__global__ __launch_bounds__(256) void k_prep(
    const float* __restrict__ x, const float* __restrict__ wqkv,
    const float* __restrict__ wout,
    short* __restrict__ xb, short* __restrict__ wqb, short* __restrict__ wob,
    float* __restrict__ cost, float* __restrict__ sint)
{
  long i = (long)blockIdx.x * 256 + threadIdx.x;
  const long n_x  = (long)MTOK * Dq;     // 2097152
  const long n_wq = (long)NQKV * Dq;     // 1572864
  const long n_wo = (long)Dq * HD;       // 524288
  const long n_tab = (long)Sq * 128;     // 262144
  if (i < n_x) { xb[i] = f2bf(x[i]); return; }
  i -= n_x;
  if (i < n_wq) { wqb[i] = f2bf(wqkv[i]); return; }
  i -= n_wq;
  if (i < n_wo) { wob[i] = f2bf(wout[i]); return; }
  i -= n_wo;
  if (i < n_tab) {
    int s = (int)(i >> 7), j = (int)(i & 127);
    double inv = pow(10000.0, -(double)j / 128.0);
    double a = (double)s * inv;
    cost[i] = (float)cos(a);
    sint[i] = (float)sin(a);
  }
}

// ---------------- GEMM: C[M,N] = A[M,K] * Bt[N,K]^T + bias (+resid) ----------------
// EPI 0: write bf16.  EPI 1: write fp32, add resid.
template<int EPI>
__global__ __launch_bounds__(256, 2) void k_gemm(
    const short* __restrict__ A, const short* __restrict__ Bt,
    const float* __restrict__ bias, const float* __restrict__ resid,
    void* __restrict__ Cp, int M, int N, int K)
{
  __shared__ short As[128 * 64];
  __shared__ short Bs[128 * 64];
  const int tid = threadIdx.x;
  const int w = tid >> 6, lane = tid & 63;
  const int grp = lane >> 4, l15 = lane & 15;
  const int wr = w >> 1, wc = w & 1;
  const int m0 = blockIdx.y * 128, n0 = blockIdx.x * 128;

  f32x4 acc[4][4];
#pragma unroll
  for (int i = 0; i < 4; i++)
#pragma unroll
    for (int j = 0; j < 4; j++) acc[i][j] = f32x4{0.f, 0.f, 0.f, 0.f};

  for (int kt = 0; kt < K; kt += 64) {
#pragma unroll
    for (int r = 0; r < 4; r++) {
      int G = r * 256 + tid;
      int row = G >> 3, gc = G & 7;
      gload16(A + (size_t)(m0 + row) * K + kt + gc * 8,
              (char*)As + (r * 256 + w * 64) * 16);
      gload16(Bt + (size_t)(n0 + row) * K + kt + gc * 8,
              (char*)Bs + (r * 256 + w * 64) * 16);
    }
    __syncthreads();
#pragma unroll
    for (int kk = 0; kk < 2; kk++) {
      short8 af[4], bf[4];
#pragma unroll
      for (int mi = 0; mi < 4; mi++) {
        int row = wr * 64 + mi * 16 + l15;
        af[mi] = *(const short8*)&As[row * 64 + kk * 32 + grp * 8];
      }
#pragma unroll
      for (int ni = 0; ni < 4; ni++) {
        int row = wc * 64 + ni * 16 + l15;
        bf[ni] = *(const short8*)&Bs[row * 64 + kk * 32 + grp * 8];
      }
#pragma unroll
      for (int mi = 0; mi < 4; mi++)
#pragma unroll
        for (int ni = 0; ni < 4; ni++)
          acc[mi][ni] = __builtin_amdgcn_mfma_f32_16x16x32_bf16(
              af[mi], bf[ni], acc[mi][ni], 0, 0, 0);
    }
    __syncthreads();
  }
#pragma unroll
  for (int mi = 0; mi < 4; mi++) {
#pragma unroll
    for (int ni = 0; ni < 4; ni++) {
      int colb = n0 + wc * 64 + ni * 16 + l15;
      float bv = bias[colb];
#pragma unroll
      for (int j = 0; j < 4; j++) {
        int row = m0 + wr * 64 + mi * 16 + grp * 4 + j;
        float v = acc[mi][ni][j] + bv;
        if (EPI == 0) {
          ((short*)Cp)[(size_t)row * N + colb] = f2bf(v);
        } else {
          size_t o = (size_t)row * N + colb;
          ((float*)Cp)[o] = v + resid[o];
        }
      }
    }
  }
}

// ---------------- RoPE in-place on q,k sections of qkv (q scaled 1/16) ----------------
__global__ __launch_bounds__(256) void k_rope(
    short* __restrict__ qkv, const float* __restrict__ cost,
    const float* __restrict__ sint)
{
  int id = blockIdx.x * 256 + threadIdx.x;   // 1048576 total
  int jv = id & 15;
  int h = (id >> 4) & 7;
  int t = id >> 7;                           // 0..8191 (= b*S+s)
  int s = t & (Sq - 1);
  size_t base = (size_t)t * NQKV + h * 256 + jv * 8;
  short8 q1 = *(const short8*)&qkv[base];
  short8 q2 = *(const short8*)&qkv[base + 128];
  short8 k1 = *(const short8*)&qkv[base + 2048];
  short8 k2 = *(const short8*)&qkv[base + 2048 + 128];
  const float* cp = &cost[(size_t)s * 128 + jv * 8];
  const float* sp = &sint[(size_t)s * 128 + jv * 8];
  short8 oq1, oq2, ok1, ok2;
#pragma unroll
  for (int e = 0; e < 8; e++) {
    float c = cp[e], sn = sp[e];
    float a = bf2f(q1[e]), b2 = bf2f(q2[e]);
    oq1[e] = f2bf((a * c - b2 * sn) * 0.0625f);
    oq2[e] = f2bf((a * sn + b2 * c) * 0.0625f);
    float ka = bf2f(k1[e]), kb = bf2f(k2[e]);
    ok1[e] = f2bf(ka * c - kb * sn);
    ok2[e] = f2bf(ka * sn + kb * c);
  }
  *(short8*)&qkv[base] = oq1;
  *(short8*)&qkv[base + 128] = oq2;
  *(short8*)&qkv[base + 2048] = ok1;
  *(short8*)&qkv[base + 2048 + 128] = ok2;
}

// ---------------- V transpose: vT[bh][d][s] = v[b,s,h,d] ----------------
__global__ __launch_bounds__(256) void k_vt(
    const short* __restrict__ qkv, short* __restrict__ vT)
{
  __shared__ short t[64][72];
  int kt = blockIdx.x, dt = blockIdx.y, bh = blockIdx.z;
  int b = bh >> 3, h = bh & 7;
  int tid = threadIdx.x;
  int r = tid >> 2, c0 = (tid & 3) * 16;
  const short* src = &qkv[(size_t)(b * Sq + kt * 64 + r) * NQKV + 4096 + h * 256 + dt * 64 + c0];
  short8 v0 = *(const short8*)src;
  short8 v1 = *(const short8*)(src + 8);
#pragma unroll
  for (int e = 0; e < 8; e++) { t[r][c0 + e] = v0[e]; t[r][c0 + 8 + e] = v1[e]; }
  __syncthreads();
  short8 o0, o1;
#pragma unroll
  for (int e = 0; e < 8; e++) { o0[e] = t[c0 + e][r]; o1[e] = t[c0 + 8 + e][r]; }
  short* dst = &vT[(size_t)(bh * 256 + dt * 64 + r) * Sq + kt * 64 + c0];
  *(short8*)dst = o0;
  *(short8*)(dst + 8) = o1;
}

// ---------------- flash attention ----------------
// grid (S/64, B*H); 4 waves, each owns 16 q-rows. KV tile = 32 keys.
__global__ __launch_bounds__(256, 2) void k_attn(
    const short* __restrict__ qkv, const short* __restrict__ vT,
    short* __restrict__ attn)
{
  __shared__ short Ks[32 * 256];     // [key][d], XOR-swizzled granules
  __shared__ short Vs[256 * 40];     // [d][key], padded 32->40
  __shared__ short Ps[4][16 * 40];   // per-wave P, padded
  const int tid = threadIdx.x;
  const int w = tid >> 6, lane = tid & 63;
  const int grp = lane >> 4, l15 = lane & 15;
  const int qb0 = blockIdx.x * 64;
  const int bh = blockIdx.y;
  const int b = bh >> 3, h = bh & 7;

  // Q fragments in registers (wave's 16 rows; q already scaled by 1/16)
  short8 qf[8];
  {
    const short* qrow = &qkv[(size_t)(b * Sq + qb0 + w * 16 + l15) * NQKV + h * 256];
#pragma unroll
    for (int kc = 0; kc < 8; kc++)
      qf[kc] = *(const short8*)&qrow[kc * 32 + grp * 8];
  }
  f32x4 o[16];
#pragma unroll
  for (int i = 0; i < 16; i++) o[i] = f32x4{0.f, 0.f, 0.f, 0.f};
  float mj[4], lj[4];
#pragma unroll
  for (int j = 0; j < 4; j++) { mj[j] = -1e30f; lj[j] = 0.f; }

  const size_t krow0 = (size_t)(b * Sq) * NQKV + 2048 + h * 256;
  const short* vbase = &vT[(size_t)bh * 256 * Sq];

  for (int kt = 0; kt < Sq / 32; kt++) {
    // ---- stage K via global_load_lds (pre-swizzled source granules) ----
#pragma unroll
    for (int r = 0; r < 4; r++) {
      int G = r * 256 + tid;
      int row = G >> 5, gc = G & 31;
      gload16(&qkv[krow0 + (size_t)(kt * 32 + row) * NQKV + (size_t)((gc ^ (row & 7)) * 8)],
              (char*)Ks + (r * 256 + w * 64) * 16);
    }
    // ---- stage V^T via registers into padded LDS ----
    short8 vstage[4];
#pragma unroll
    for (int r = 0; r < 4; r++) {
      int G = r * 256 + tid;
      vstage[r] = *(const short8*)&vbase[(size_t)(G >> 2) * Sq + kt * 32 + (G & 3) * 8];
    }
#pragma unroll
    for (int r = 0; r < 4; r++) {
      int G = r * 256 + tid;
      *(short8*)&Vs[(G >> 2) * 40 + (G & 3) * 8] = vstage[r];
    }
    __syncthreads();

    // ---- QK^T: scores[16 rows][32 keys] per wave ----
    f32x4 sc[2];
#pragma unroll
    for (int nt = 0; nt < 2; nt++) sc[nt] = f32x4{0.f, 0.f, 0.f, 0.f};
#pragma unroll
    for (int kc = 0; kc < 8; kc++) {
#pragma unroll
      for (int nt = 0; nt < 2; nt++) {
        int row = nt * 16 + l15;
        int byteoff = (row * 512 + kc * 64 + grp * 16) ^ ((row & 7) << 4);
        short8 bf = *(const short8*)((const char*)Ks + byteoff);
        sc[nt] = __builtin_amdgcn_mfma_f32_16x16x32_bf16(qf[kc], bf, sc[nt], 0, 0, 0);
      }
    }

    // ---- online softmax (rows = grp*4+j, cols across 16-lane group x 2 tiles) ----
    float p[2][4], nm[4], f[4];
    bool up = false;
#pragma unroll
    for (int j = 0; j < 4; j++) {
      float mx = fmaxf(sc[0][j], sc[1][j]);
#pragma unroll
      for (int m = 1; m < 16; m <<= 1) mx = fmaxf(mx, __shfl_xor(mx, m, 64));
      nm[j] = fmaxf(mj[j], mx);
      up = up || (nm[j] > mj[j]);
      f[j] = __expf(mj[j] - nm[j]);
      float rs = 0.f;
#pragma unroll
      for (int nt = 0; nt < 2; nt++) { p[nt][j] = __expf(sc[nt][j] - nm[j]); rs += p[nt][j]; }
#pragma unroll
      for (int m = 1; m < 16; m <<= 1) rs += __shfl_xor(rs, m, 64);
      lj[j] = lj[j] * f[j] + rs;
    }
    if (__any(up)) {
#pragma unroll
      for (int vt = 0; vt < 16; vt++)
#pragma unroll
        for (int j = 0; j < 4; j++) o[vt][j] *= f[j];
    }
#pragma unroll
    for (int j = 0; j < 4; j++) mj[j] = nm[j];

    // ---- P -> LDS (wave-private region) ----
#pragma unroll
    for (int nt = 0; nt < 2; nt++)
#pragma unroll
      for (int j = 0; j < 4; j++)
        Ps[w][(grp * 4 + j) * 40 + nt * 16 + l15] = f2bf(p[nt][j]);

    // ---- PV (same-wave LDS RAW: compiler inserts lgkmcnt waits) ----
    short8 af = *(const short8*)&Ps[w][l15 * 40 + grp * 8];
#pragma unroll
    for (int vt = 0; vt < 16; vt++) {
      short8 bf = *(const short8*)&Vs[(vt * 16 + l15) * 40 + grp * 8];
      o[vt] = __builtin_amdgcn_mfma_f32_16x16x32_bf16(af, bf, o[vt], 0, 0, 0);
    }
    __syncthreads();
  }

  // ---- finalize: /l and store bf16 to attn[b,s, h*256+d] ----
  float inv[4];
#pragma unroll
  for (int j = 0; j < 4; j++) inv[j] = 1.0f / lj[j];
  short* orow = &attn[(size_t)(b * Sq + qb0 + w * 16) * HD + h * 256];
#pragma unroll
  for (int vt = 0; vt < 16; vt++)
#pragma unroll
    for (int j = 0; j < 4; j++)
      orow[(size_t)(grp * 4 + j) * HD + vt * 16 + l15] = f2bf(o[vt][j] * inv[j]);
}

// ---------------- launch ----------------
extern "C" void kernel_launch(void* const* d_in, const int* in_sizes, int n_in,
                              void* d_out, int out_size, void* d_ws, size_t ws_size,
                              hipStream_t stream) {
  const float* x     = (const float*)d_in[0];
  const float* w_qkv = (const float*)d_in[1];
  const float* b_qkv = (const float*)d_in[2];
  const float* w_out = (const float*)d_in[3];
  const float* b_out = (const float*)d_in[4];
  float* out = (float*)d_out;

  char* ws = (char*)d_ws;
  short* qkv  = (short*)ws;                               // 100663296 B
  short* vT   = (short*)(ws + 100663296);                 // 33554432 B
  short* attn = (short*)(ws + 134217728);                 // 33554432 B
  short* xb   = (short*)(ws + 167772160);                 // 4194304 B
  short* wqb  = (short*)(ws + 171966464);                 // 3145728 B
  short* wob  = (short*)(ws + 175112192);                 // 1048576 B
  float* cost = (float*)(ws + 176160768);                 // 1048576 B
  float* sint = (float*)(ws + 177209344);                 // 1048576 B -> 178257920 total

  k_prep<<<dim3(17408), 256, 0, stream>>>(x, w_qkv, w_out, xb, wqb, wob, cost, sint);
  k_gemm<0><<<dim3(NQKV / 128, MTOK / 128), 256, 0, stream>>>(
      xb, wqb, b_qkv, nullptr, qkv, MTOK, NQKV, Dq);
  k_rope<<<dim3(4096), 256, 0, stream>>>(qkv, cost, sint);
  k_vt<<<dim3(32, 4, 32), 256, 0, stream>>>(qkv, vT);
  k_attn<<<dim3(32, 32), 256, 0, stream>>>(qkv, vT, attn);
  k_gemm<1><<<dim3(Dq / 128, MTOK / 128), 256, 0, stream>>>(
      attn, wob, b_out, x, out, MTOK, Dq, HD);
}